// Round 6
// baseline (311.620 us; speedup 1.0000x reference)
//
#include <hip/hip_runtime.h>

// GRU H=31, B=2048, T=512, FC->2, three-phase:
//  1) pack_wih:  W_ih -> packed f16 pairs in ws (93 rows x 16 pairs)
//  2) xg_gemm:   xg[b][row][t] = b_ih[row] + x[b,t,:] . W_ih[row,:]  (f16, ws)
//  3) gru_rec:   1 batch per wave64 (2048 waves = 2/SIMD).
//     lane li (half = lane>>5): rz-row = half*31+li (full K, 16 dot2),
//     n-row li with K split across halves (8 dot2).
//     Cross-half combines now use v_permlane32_swap (VALU, ~4cy) instead of
//     __shfl_xor (DS pipe, ~120cy on the critical path):
//       with P = permlane32_swap(v,v): {P0,P1} = {lo-bcast, hi-bcast} in some
//       order, so  P0+P1 = v.lo+v.hi  (exact n-combine, order-independent)
//       and        P0+P1-v = xor32-swap(v)  (rz exchange).
//     Lane 31 carries the FC head rows on its rz stream (xg pad rows zero).
//     h broadcast via per-wave LDS f16[32]; in-wave DS ordering + explicit
//     compiler memory fences (r4 lesson: clang reordered the _Float16
//     ds_write vs int4 ds_read across TBAA types).

constexpr int BB = 2048, TT = 512, HH = 31;
constexpr int RR = 96;                                  // padded xg rows
constexpr size_t XG_BYTES = (size_t)BB * RR * TT * 2;   // 201326592
constexpr int WPAIRS = 93 * 16;
constexpr size_t WS_NEEDED = XG_BYTES + (size_t)WPAIRS * 4;

#define MEMFENCE asm volatile("" ::: "memory")

typedef _Float16 hf2 __attribute__((ext_vector_type(2)));

__device__ __forceinline__ float dot2(int a, hf2 w, float acc) {
#if __has_builtin(__builtin_amdgcn_fdot2)
    return __builtin_amdgcn_fdot2(__builtin_bit_cast(hf2, a), w, acc, false);
#else
    hf2 x = __builtin_bit_cast(hf2, a);
    return acc + (float)x.x * (float)x.x * 0.f + (float)x.x * (float)w.x + (float)x.y * (float)w.y;
#endif
}

// Sum of the two 32-lane halves' values of v (uniform within pair), and the
// xor-32 swapped value. Both derived from one permlane32_swap, with
// identities that hold under either possible swap-direction semantic.
#if __has_builtin(__builtin_amdgcn_permlane32_swap)
__device__ __forceinline__ float half_sum(float v) {
    auto p = __builtin_amdgcn_permlane32_swap(
        __builtin_bit_cast(unsigned, v), __builtin_bit_cast(unsigned, v),
        false, false);
    return __builtin_bit_cast(float, (unsigned)p[0]) +
           __builtin_bit_cast(float, (unsigned)p[1]);
}
__device__ __forceinline__ float xor32_swap(float v) {
    return half_sum(v) - v;
}
#else
__device__ __forceinline__ float half_sum(float v) {
    return v + __shfl_xor(v, 32);
}
__device__ __forceinline__ float xor32_swap(float v) {
    return __shfl_xor(v, 32);
}
#endif

// ---------------- phase 1a: pack W_ih to f16 pairs ----------------
__global__ void pack_wih_kernel(const float* __restrict__ W_ih, int* __restrict__ wpk) {
    int q = blockIdx.x * blockDim.x + threadIdx.x;
    if (q >= WPAIRS) return;
    int row = q >> 4, p = q & 15;
    float lo = W_ih[row * HH + 2 * p];
    float hi = (2 * p + 1 < HH) ? W_ih[row * HH + 2 * p + 1] : 0.f;
    hf2 w; w.x = (_Float16)lo; w.y = (_Float16)hi;
    wpk[q] = __builtin_bit_cast(int, w);
}

// ---------------- phase 1b: xg = x @ W_ih^T + b_ih ----------------
__global__ __launch_bounds__(128, 2) void xg_gemm_kernel(
    const float* __restrict__ x, const int* __restrict__ wpk,
    const float* __restrict__ b_ih, _Float16* __restrict__ xg)
{
    const int tid = threadIdx.x;
    const int b   = blockIdx.x;
    const int t0  = tid * 4;                     // 4 consecutive timesteps
    const float* xb = x + ((size_t)b * TT + t0) * HH;

    hf2 xp[4][16];
#pragma unroll
    for (int j = 0; j < 4; ++j)
#pragma unroll
        for (int p = 0; p < 16; ++p) {
            float lo = xb[j * HH + 2 * p];
            float hi = (2 * p + 1 < HH) ? xb[j * HH + 2 * p + 1] : 0.f;
            xp[j][p].x = (_Float16)lo; xp[j][p].y = (_Float16)hi;
        }

    _Float16* xgb = xg + (size_t)b * RR * TT + t0;
    for (int row = 0; row < 93; ++row) {
        const float bi = b_ih[row];                       // uniform -> s_load
        float a0 = bi, a1 = bi, a2 = bi, a3 = bi;
        const int* wr = wpk + row * 16;                   // uniform -> s_load
#pragma unroll
        for (int p = 0; p < 16; ++p) {
            const int w = wr[p];
            a0 = dot2(w, xp[0][p], a0);
            a1 = dot2(w, xp[1][p], a1);
            a2 = dot2(w, xp[2][p], a2);
            a3 = dot2(w, xp[3][p], a3);
        }
        hf2 lo2; lo2.x = (_Float16)a0; lo2.y = (_Float16)a1;
        hf2 hi2; hi2.x = (_Float16)a2; hi2.y = (_Float16)a3;
        *reinterpret_cast<int2*>(xgb + (size_t)row * TT) =
            make_int2(__builtin_bit_cast(int, lo2), __builtin_bit_cast(int, hi2));
    }
    for (int row = 93; row < 96; ++row)       // zero pad rows (lane31 reads)
        *reinterpret_cast<int2*>(xgb + (size_t)row * TT) = make_int2(0, 0);
}

// ---------------- phase 2: recurrence, 1 batch/wave ----------------
__global__ __launch_bounds__(256, 2) void gru_rec_kernel(
    const _Float16* __restrict__ xg, const float* __restrict__ W_hh,
    const float* __restrict__ b_hh, const float* __restrict__ W_fc,
    const float* __restrict__ b_fc, float* __restrict__ out)
{
    __shared__ _Float16 hbuf[4][32];
    const int tid = threadIdx.x, wv = tid >> 6, lane = tid & 63;
    const int li = lane & 31, half = lane >> 5;
    const int b  = blockIdx.x * 4 + wv;
    const bool u = (li < HH);

    // rz stream: unit lanes get W_hh r-row (low) / z-row (high); lane31: W_fc row.
    const float* pA = u ? W_hh + (size_t)(half * HH + li) * HH : W_fc + half * HH;
    const float* pN = W_hh + (size_t)(2 * HH + (u ? li : 0)) * HH;
    const float bA0 = u ? b_hh[half * HH + li] : b_fc[half];
    const float bN0 = (u && half == 0) ? b_hh[2 * HH + li] : 0.f;

    // wA packed with +8*half pair rotation, matching rotated h-chunk reads.
    hf2 wA[16], wN[8];
#pragma unroll
    for (int p = 0; p < 16; ++p) {
        const int pp = (p + 8 * half) & 15;
        float lo = pA[2 * pp];
        float hi = (2 * pp + 1 < HH) ? pA[2 * pp + 1] : 0.f;
        wA[p].x = (_Float16)lo; wA[p].y = (_Float16)hi;
    }
#pragma unroll
    for (int p = 0; p < 8; ++p) {
        const int pp = 8 * half + p;               // low: k0..15, high: k16..31
        float lo = u ? pN[2 * pp] : 0.f;
        float hi = (u && 2 * pp + 1 < HH) ? pN[2 * pp + 1] : 0.f;
        wN[p].x = (_Float16)lo; wN[p].y = (_Float16)hi;
    }

    const int rowA = u ? half * HH + li : 93 + half;   // pad rows are zero
    const int rowN = u ? 2 * HH + li : 95;
    const _Float16* gA = xg + ((size_t)b * RR + rowA) * TT;
    const _Float16* gN = xg + ((size_t)b * RR + rowN) * TT;
    float* outb = out + (size_t)b * TT * 2;

    if (half == 0) hbuf[wv][li] = (_Float16)0.f;   // h_0 = 0 (incl lane31 pad)
    MEMFENCE;

    const int4* HP = (const int4*)&hbuf[wv][0];
    const int i0 = (0 + 2 * half) & 3, i1 = (1 + 2 * half) & 3,
              i2 = (2 + 2 * half) & 3, i3 = (3 + 2 * half) & 3;

    int4 bufA = *(const int4*)gA;
    int4 bufN = *(const int4*)gN;
    float hval = 0.f;

    for (int tb = 0; tb < TT / 8; ++tb) {
        int4 nxtA = bufA, nxtN = bufN;
        if (tb + 1 < TT / 8) {
            nxtA = *(const int4*)(gA + (size_t)(tb + 1) * 8);
            nxtN = *(const int4*)(gN + (size_t)(tb + 1) * 8);
        }
#pragma unroll
        for (int s = 0; s < 8; ++s) {
            const int t = tb * 8 + s;
            const int4 h0 = HP[i0], h1 = HP[i1], h2 = HP[i2], h3 = HP[i3];
            const float xa = (float)(((const _Float16*)&bufA)[s]);
            const float xn = (float)(((const _Float16*)&bufN)[s]);

            // n dots first (8): rotated chunks h0,h1 = this half's K-half.
            float n0 = bN0, n1 = 0.f;
            n0 = dot2(h0.x, wN[0], n0); n1 = dot2(h0.y, wN[1], n1);
            n0 = dot2(h0.z, wN[2], n0); n1 = dot2(h0.w, wN[3], n1);
            n0 = dot2(h1.x, wN[4], n0); n1 = dot2(h1.y, wN[5], n1);
            n0 = dot2(h1.z, wN[6], n0); n1 = dot2(h1.w, wN[7], n1);
            const float accN = n0 + n1;
            const float nh = half_sum(accN);   // W_hh_n.h + b_hh_n (exact sum
                                               // of both halves' partials)

            float a0v = bA0 + xa, a1v = 0.f;
            a0v = dot2(h0.x, wA[0], a0v);  a1v = dot2(h0.y, wA[1], a1v);
            a0v = dot2(h0.z, wA[2], a0v);  a1v = dot2(h0.w, wA[3], a1v);
            a0v = dot2(h1.x, wA[4], a0v);  a1v = dot2(h1.y, wA[5], a1v);
            a0v = dot2(h1.z, wA[6], a0v);  a1v = dot2(h1.w, wA[7], a1v);
            a0v = dot2(h2.x, wA[8], a0v);  a1v = dot2(h2.y, wA[9], a1v);
            a0v = dot2(h2.z, wA[10], a0v); a1v = dot2(h2.w, wA[11], a1v);
            a0v = dot2(h3.x, wA[12], a0v); a1v = dot2(h3.y, wA[13], a1v);
            a0v = dot2(h3.z, wA[14], a0v); a1v = dot2(h3.w, wA[15], a1v);
            const float accA = a0v + a1v;   // r|z pre-act; lane31: FC(h_{t-1})
            const float asw = xor32_swap(accA);

            if (li == 31 && t > 0) outb[(size_t)(t - 1) * 2 + half] = accA;

            const float g  = __fdividef(1.f, 1.f + __expf(-accA));
            const float go = __fdividef(1.f, 1.f + __expf(-asw));
            const float r = half ? go : g;
            const float z = half ? g  : go;
            const float npre = fmaf(r, nh, xn);
            const float nn   = __fdividef(2.f, 1.f + __expf(-2.f * npre)) - 1.f;
            const float hnew = nn + z * (hval - nn);
            hval = u ? hnew : 0.f;                     // lane31 pad stays 0
            if (half == 0) hbuf[wv][li] = (_Float16)hval;
            MEMFENCE;   // order ds_write vs next step's ds_read (r4 bug fix)
        }
        bufA = nxtA; bufN = nxtN;
    }

    // epilogue: FC(h_{T-1}) from lane31's rz stream (no xg term)
    {
        const int4 h0 = HP[i0], h1 = HP[i1], h2 = HP[i2], h3 = HP[i3];
        float a0v = bA0, a1v = 0.f;
        a0v = dot2(h0.x, wA[0], a0v);  a1v = dot2(h0.y, wA[1], a1v);
        a0v = dot2(h0.z, wA[2], a0v);  a1v = dot2(h0.w, wA[3], a1v);
        a0v = dot2(h1.x, wA[4], a0v);  a1v = dot2(h1.y, wA[5], a1v);
        a0v = dot2(h1.z, wA[6], a0v);  a1v = dot2(h1.w, wA[7], a1v);
        a0v = dot2(h2.x, wA[8], a0v);  a1v = dot2(h2.y, wA[9], a1v);
        a0v = dot2(h2.z, wA[10], a0v); a1v = dot2(h2.w, wA[11], a1v);
        a0v = dot2(h3.x, wA[12], a0v); a1v = dot2(h3.y, wA[13], a1v);
        a0v = dot2(h3.z, wA[14], a0v); a1v = dot2(h3.w, wA[15], a1v);
        if (li == 31) outb[(size_t)(TT - 1) * 2 + half] = a0v + a1v;
    }
}

// ---------------- fallback (round-3 kernel, used if ws too small) ----------------
__global__ __launch_bounds__(64, 1) void gru_pair_kernel(
    const float* __restrict__ x, const float* __restrict__ W_ih,
    const float* __restrict__ W_hh, const float* __restrict__ b_ih,
    const float* __restrict__ b_hh, const float* __restrict__ W_fc,
    const float* __restrict__ b_fc, float* __restrict__ out)
{
    __shared__ _Float16 hbuf[2][32];
    __shared__ _Float16 xbuf[2][2][32];

    const int lane = threadIdx.x & 63;
    const int li   = lane & 31;
    const int half = lane >> 5;
    const int b    = blockIdx.x * 2 + half;
    const bool unit = (li < HH);

    const float* ph0 = unit ? W_hh + (size_t)li * HH            : W_fc;
    const float* ph1 = unit ? W_hh + (size_t)(HH + li) * HH     : W_fc + HH;
    const float* ph2 = unit ? W_hh + (size_t)(2 * HH + li) * HH : nullptr;
    const float* px0 = unit ? W_ih + (size_t)li * HH            : nullptr;
    const float* px1 = unit ? W_ih + (size_t)(HH + li) * HH     : nullptr;
    const float* px2 = unit ? W_ih + (size_t)(2 * HH + li) * HH : nullptr;

    hf2 wh0[16], wh1[16], wh2[16], wx0[16], wx1[16], wx2[16];
#pragma unroll
    for (int m = 0; m < 16; ++m) {
        auto pk = [&](const float* p) -> hf2 {
            hf2 r;
            r.x = p ? (_Float16)p[2 * m] : (_Float16)0.f;
            r.y = (p && (2 * m + 1) < HH) ? (_Float16)p[2 * m + 1] : (_Float16)0.f;
            return r;
        };
        wh0[m] = pk(ph0); wh1[m] = pk(ph1); wh2[m] = pk(ph2);
        wx0[m] = pk(px0); wx1[m] = pk(px1); wx2[m] = pk(px2);
    }

    float arH0, azH0, anH0, anX0;
    if (unit) {
        arH0 = b_ih[li] + b_hh[li];
        azH0 = b_ih[HH + li] + b_hh[HH + li];
        anH0 = b_hh[2 * HH + li];
        anX0 = b_ih[2 * HH + li];
    } else {
        arH0 = b_fc[0]; azH0 = b_fc[1]; anH0 = 0.f; anX0 = 0.f;
    }

    const float* xb   = x + (size_t)b * TT * HH;
    float*       outb = out + (size_t)b * TT * 2;

    hbuf[half][li]    = (_Float16)0.f;
    xbuf[0][half][li] = unit ? (_Float16)xb[li]      : (_Float16)0.f;
    xbuf[1][half][li] = unit ? (_Float16)xb[HH + li] : (_Float16)0.f;
    MEMFENCE;
    float xpre = unit ? xb[(size_t)2 * HH + li] : 0.f;
    float hval = 0.f;

    const int4* HP  = (const int4*)(&hbuf[half][0]);
    const int4* XB0 = (const int4*)(&xbuf[0][half][0]);
    const int4* XB1 = (const int4*)(&xbuf[1][half][0]);

    int4 xq0 = XB0[0], xq1 = XB0[1], xq2 = XB0[2], xq3 = XB0[3];

#pragma unroll 2
    for (int t = 0; t < TT; ++t) {
        int4 hq0 = HP[0], hq1 = HP[1], hq2 = HP[2], hq3 = HP[3];

        float arH = arH0, azH = azH0, anH = anH0;
        float arX = 0.f, azX = 0.f, anX = anX0;
#define STEPM(m, hp, xp) \
        arH = dot2(hp, wh0[m], arH); azH = dot2(hp, wh1[m], azH); \
        anH = dot2(hp, wh2[m], anH); arX = dot2(xp, wx0[m], arX); \
        azX = dot2(xp, wx1[m], azX); anX = dot2(xp, wx2[m], anX);
        STEPM(0,  hq0.x, xq0.x) STEPM(1,  hq0.y, xq0.y)
        STEPM(2,  hq0.z, xq0.z) STEPM(3,  hq0.w, xq0.w)
        STEPM(4,  hq1.x, xq1.x) STEPM(5,  hq1.y, xq1.y)
        STEPM(6,  hq1.z, xq1.z) STEPM(7,  hq1.w, xq1.w)
        STEPM(8,  hq2.x, xq2.x) STEPM(9,  hq2.y, xq2.y)
        STEPM(10, hq2.z, xq2.z) STEPM(11, hq2.w, xq2.w)
        STEPM(12, hq3.x, xq3.x) STEPM(13, hq3.y, xq3.y)
        STEPM(14, hq3.z, xq3.z) STEPM(15, hq3.w, xq3.w)
#undef STEPM

        const float sumr = arH + arX;
        const float sumz = azH + azX;
        if (lane == 31 && t > 0)
            *(float2*)(outb + (size_t)(t - 1) * 2) = make_float2(sumr, sumz);

        const float r    = __fdividef(1.f, 1.f + __expf(-sumr));
        const float z    = __fdividef(1.f, 1.f + __expf(-sumz));
        const float npre = fmaf(r, anH, anX);
        const float nn   = __fdividef(2.f, 1.f + __expf(-2.f * npre)) - 1.f;
        const float hnew = nn + z * (hval - nn);
        hval = unit ? hnew : 0.f;
        hbuf[half][li] = (_Float16)hval;

        xbuf[t & 1][half][li] = unit ? (_Float16)xpre : (_Float16)0.f;
        MEMFENCE;
        int tn = t + 3; if (tn > TT - 1) tn = TT - 1;
        xpre = unit ? xb[(size_t)tn * HH + li] : 0.f;

        const int4* XN = (t & 1) ? XB0 : XB1;
        xq0 = XN[0]; xq1 = XN[1]; xq2 = XN[2]; xq3 = XN[3];
    }

    {
        int4 hq0 = HP[0], hq1 = HP[1], hq2 = HP[2], hq3 = HP[3];
        float f0 = arH0, f1 = azH0;
#define FST(m, hp) f0 = dot2(hp, wh0[m], f0); f1 = dot2(hp, wh1[m], f1);
        FST(0,  hq0.x) FST(1,  hq0.y) FST(2,  hq0.z) FST(3,  hq0.w)
        FST(4,  hq1.x) FST(5,  hq1.y) FST(6,  hq1.z) FST(7,  hq1.w)
        FST(8,  hq2.x) FST(9,  hq2.y) FST(10, hq2.z) FST(11, hq2.w)
        FST(12, hq3.x) FST(13, hq3.y) FST(14, hq3.z) FST(15, hq3.w)
#undef FST
        if (lane == 31)
            *(float2*)(outb + (size_t)(TT - 1) * 2) = make_float2(f0, f1);
    }
}

extern "C" void kernel_launch(void* const* d_in, const int* in_sizes, int n_in,
                              void* d_out, int out_size, void* d_ws, size_t ws_size,
                              hipStream_t stream) {
    const float* x    = (const float*)d_in[0];
    const float* W_ih = (const float*)d_in[1];
    const float* W_hh = (const float*)d_in[2];
    const float* b_ih = (const float*)d_in[3];
    const float* b_hh = (const float*)d_in[4];
    const float* W_fc = (const float*)d_in[5];
    const float* b_fc = (const float*)d_in[6];
    float* out = (float*)d_out;

    if (ws_size >= WS_NEEDED) {
        _Float16* xg = (_Float16*)d_ws;
        int* wpk = (int*)((char*)d_ws + XG_BYTES);
        pack_wih_kernel<<<(WPAIRS + 255) / 256, 256, 0, stream>>>(W_ih, wpk);
        xg_gemm_kernel<<<BB, 128, 0, stream>>>(x, wpk, b_ih, xg);
        gru_rec_kernel<<<BB / 4, 256, 0, stream>>>(xg, W_hh, b_hh, W_fc, b_fc, out);
    } else {
        gru_pair_kernel<<<BB / 2, 64, 0, stream>>>(x, W_ih, W_hh, b_ih, b_hh,
                                                   W_fc, b_fc, out);
    }
}

// Round 7
// 299.429 us; speedup vs baseline: 1.0407x; 1.0407x over previous
//
#include <hip/hip_runtime.h>

// GRU H=31, B=2048, T=512, FC->2, three-phase:
//  1) pack_wih: W_ih -> packed f16 pairs in ws, PRE-SCALED (r/z rows x log2e,
//     n rows x 2log2e) so the recurrence uses v_exp (=2^x) natively.
//  2) xg_gemm:  xg[b][row][t] = (b_ih[row] + x . W_ih[row]) * scale  (f16, ws)
//  3) gru_rec:  1 batch per wave64 (2048 waves = 2/SIMD). NO LDS:
//     h broadcast all-VALU: cvt_pkrtz -> DPP quad_perm xor1 -> v_perm pair
//     -> 16x v_readlane -> SGPR pairs feed v_dot2 (SGPR src0, 1 per inst).
//     lane li (half=lane>>5): rz-row = half*31+li (16 dot2, scaled log2e),
//     n-row li full-K (16 dot2, scaled 2log2e, lane-local accN).
//     r/z cross-half exchange via permlane32_swap identity (r6-verified).
//     Lane 31 carries the FC head rows (unscaled) on its rz stream.
//     Gates: sigmoid = rcp(1+exp2(-a')), tanh = 2*rcp(1+exp2(-n'))-1.

constexpr int BB = 2048, TT = 512, HH = 31;
constexpr int RR = 96;                                  // padded xg rows
constexpr size_t XG_BYTES = (size_t)BB * RR * TT * 2;   // 201326592
constexpr int WPAIRS = 93 * 16;
constexpr size_t WS_NEEDED = XG_BYTES + (size_t)WPAIRS * 4;
constexpr float LOG2E = 1.4426950408889634f;

#define MEMFENCE asm volatile("" ::: "memory")

typedef _Float16 hf2 __attribute__((ext_vector_type(2)));

__device__ __forceinline__ float dot2(int a, hf2 w, float acc) {
#if __has_builtin(__builtin_amdgcn_fdot2)
    return __builtin_amdgcn_fdot2(__builtin_bit_cast(hf2, a), w, acc, false);
#else
    hf2 x = __builtin_bit_cast(hf2, a);
    return acc + (float)x.x * (float)w.x + (float)x.y * (float)w.y;
#endif
}

__device__ __forceinline__ float fast_exp2(float x) {
#if __has_builtin(__builtin_amdgcn_exp2f)
    return __builtin_amdgcn_exp2f(x);
#else
    return exp2f(x);
#endif
}
__device__ __forceinline__ float fast_rcp(float x) {
#if __has_builtin(__builtin_amdgcn_rcpf)
    return __builtin_amdgcn_rcpf(x);
#else
    return __fdividef(1.f, x);
#endif
}

// half-sum / xor32 swap via permlane32_swap (verified numerically in r6).
#if __has_builtin(__builtin_amdgcn_permlane32_swap)
__device__ __forceinline__ float xor32_swap(float v) {
    auto p = __builtin_amdgcn_permlane32_swap(
        __builtin_bit_cast(unsigned, v), __builtin_bit_cast(unsigned, v),
        false, false);
    return __builtin_bit_cast(float, (unsigned)p[0]) +
           __builtin_bit_cast(float, (unsigned)p[1]) - v;
}
#else
__device__ __forceinline__ float xor32_swap(float v) { return __shfl_xor(v, 32); }
#endif

// All-VALU broadcast of per-lane h (lanes 0..31 hold units 0..31, replicated
// in the high half) into 16 wave-uniform packed-f16 pairs.
__device__ __forceinline__ void bcast_h(float hv, int hs[16]) {
    const int pk = __builtin_bit_cast(int, __builtin_amdgcn_cvt_pkrtz(hv, hv));
#if __has_builtin(__builtin_amdgcn_update_dpp)
    const int nb = __builtin_amdgcn_update_dpp(0, pk, 0xB1, 0xF, 0xF, true); // quad_perm [1,0,3,2] = xor1
#else
    const int nb = __shfl_xor(pk, 1);
#endif
    const int pr = __builtin_amdgcn_perm(nb, pk, 0x05040100); // {own, neighbor}
#pragma unroll
    for (int m = 0; m < 16; ++m)
        hs[m] = __builtin_amdgcn_readlane(pr, 2 * m);
}

// ---------------- phase 1a: pack W_ih to scaled f16 pairs ----------------
__global__ void pack_wih_kernel(const float* __restrict__ W_ih, int* __restrict__ wpk) {
    int q = blockIdx.x * blockDim.x + threadIdx.x;
    if (q >= WPAIRS) return;
    int row = q >> 4, p = q & 15;
    const float s = (row < 62) ? LOG2E : 2.f * LOG2E;
    float lo = W_ih[row * HH + 2 * p] * s;
    float hi = (2 * p + 1 < HH) ? W_ih[row * HH + 2 * p + 1] * s : 0.f;
    hf2 w; w.x = (_Float16)lo; w.y = (_Float16)hi;
    wpk[q] = __builtin_bit_cast(int, w);
}

// ---------------- phase 1b: xg = (x @ W_ih^T + b_ih) * scale ----------------
__global__ __launch_bounds__(128, 2) void xg_gemm_kernel(
    const float* __restrict__ x, const int* __restrict__ wpk,
    const float* __restrict__ b_ih, _Float16* __restrict__ xg)
{
    const int tid = threadIdx.x;
    const int b   = blockIdx.x;
    const int t0  = tid * 4;                     // 4 consecutive timesteps
    const float* xb = x + ((size_t)b * TT + t0) * HH;

    hf2 xp[4][16];
#pragma unroll
    for (int j = 0; j < 4; ++j)
#pragma unroll
        for (int p = 0; p < 16; ++p) {
            float lo = xb[j * HH + 2 * p];
            float hi = (2 * p + 1 < HH) ? xb[j * HH + 2 * p + 1] : 0.f;
            xp[j][p].x = (_Float16)lo; xp[j][p].y = (_Float16)hi;
        }

    _Float16* xgb = xg + (size_t)b * RR * TT + t0;
    for (int row = 0; row < 93; ++row) {
        const float bi = b_ih[row] * ((row < 62) ? LOG2E : 2.f * LOG2E);
        float a0 = bi, a1 = bi, a2 = bi, a3 = bi;
        const int* wr = wpk + row * 16;                   // uniform -> s_load
#pragma unroll
        for (int p = 0; p < 16; ++p) {
            const int w = wr[p];
            a0 = dot2(w, xp[0][p], a0);
            a1 = dot2(w, xp[1][p], a1);
            a2 = dot2(w, xp[2][p], a2);
            a3 = dot2(w, xp[3][p], a3);
        }
        hf2 lo2; lo2.x = (_Float16)a0; lo2.y = (_Float16)a1;
        hf2 hi2; hi2.x = (_Float16)a2; hi2.y = (_Float16)a3;
        *reinterpret_cast<int2*>(xgb + (size_t)row * TT) =
            make_int2(__builtin_bit_cast(int, lo2), __builtin_bit_cast(int, hi2));
    }
    for (int row = 93; row < 96; ++row)       // zero pad rows (lane31 reads)
        *reinterpret_cast<int2*>(xgb + (size_t)row * TT) = make_int2(0, 0);
}

// ---------------- phase 2: recurrence, 1 batch/wave, zero LDS ----------------
__global__ __launch_bounds__(256, 2) void gru_rec_kernel(
    const _Float16* __restrict__ xg, const float* __restrict__ W_hh,
    const float* __restrict__ b_hh, const float* __restrict__ W_fc,
    const float* __restrict__ b_fc, float* __restrict__ out)
{
    const int tid = threadIdx.x, wv = tid >> 6, lane = tid & 63;
    const int li = lane & 31, half = lane >> 5;
    const int b  = blockIdx.x * 4 + wv;
    const bool u = (li < HH);

    const float sA = u ? LOG2E : 1.f;          // lane31 = FC head, unscaled
    const float sN = 2.f * LOG2E;
    const float* pA = u ? W_hh + (size_t)(half * HH + li) * HH
                        : W_fc + (size_t)half * HH;
    const float* pN = W_hh + (size_t)(2 * HH + (u ? li : 0)) * HH;
    const float bA0 = (u ? b_hh[half * HH + li] : b_fc[half]) * sA;
    const float bN0 = u ? b_hh[2 * HH + li] * sN : 0.f;

    hf2 wA[16], wN[16];
#pragma unroll
    for (int p = 0; p < 16; ++p) {
        const float alo = pA[2 * p];
        const float ahi = (2 * p + 1 < HH) ? pA[2 * p + 1] : 0.f;
        wA[p].x = (_Float16)(alo * sA); wA[p].y = (_Float16)(ahi * sA);
        const float nlo = u ? pN[2 * p] : 0.f;
        const float nhi = (u && 2 * p + 1 < HH) ? pN[2 * p + 1] : 0.f;
        wN[p].x = (_Float16)(nlo * sN); wN[p].y = (_Float16)(nhi * sN);
    }

    const int rowA = u ? half * HH + li : 93 + half;   // pad rows are zero
    const int rowN = u ? 2 * HH + li : 95;
    const _Float16* gA = xg + ((size_t)b * RR + rowA) * TT;
    const _Float16* gN = xg + ((size_t)b * RR + rowN) * TT;
    float* outb = out + (size_t)b * TT * 2;

    float hval = 0.f;
    int hs[16];
    bcast_h(0.f, hs);                          // h_0 = 0

    int4 bufA = *(const int4*)gA;
    int4 bufN = *(const int4*)gN;

    for (int tb = 0; tb < TT / 8; ++tb) {
        int4 nxtA = bufA, nxtN = bufN;
        if (tb + 1 < TT / 8) {
            nxtA = *(const int4*)(gA + (size_t)(tb + 1) * 8);
            nxtN = *(const int4*)(gN + (size_t)(tb + 1) * 8);
        }
#pragma unroll
        for (int s = 0; s < 8; ++s) {
            const int t = tb * 8 + s;
            const float xa = (float)(((const _Float16*)&bufA)[s]);
            const float xn = (float)(((const _Float16*)&bufN)[s]);

            float a0 = bA0 + xa, a1 = 0.f, n0 = bN0, n1 = 0.f;
#pragma unroll
            for (int m = 0; m < 16; m += 2) {
                a0 = dot2(hs[m],     wA[m],     a0);
                a1 = dot2(hs[m + 1], wA[m + 1], a1);
                n0 = dot2(hs[m],     wN[m],     n0);
                n1 = dot2(hs[m + 1], wN[m + 1], n1);
            }
            const float accA = a0 + a1;   // log2e*(r|z pre); lane31: FC(h_{t-1})
            const float accN = n0 + n1;   // 2log2e*(W_hh_n.h + b_hh_n)
            const float asw = xor32_swap(accA);

            if (li == 31 && t > 0) outb[(size_t)(t - 1) * 2 + half] = accA;

            const float g  = fast_rcp(1.f + fast_exp2(-accA));
            const float go = fast_rcp(1.f + fast_exp2(-asw));
            const float r = half ? go : g;
            const float z = half ? g : go;
            const float en = fast_exp2(fmaf(-r, accN, -xn));   // e^{-2 npre}
            const float nn = fmaf(2.f, fast_rcp(1.f + en), -1.f);
            const float hnew = nn + z * (hval - nn);
            hval = u ? hnew : 0.f;                     // lane31 pad stays 0
            bcast_h(hval, hs);
        }
        bufA = nxtA; bufN = nxtN;
    }

    // epilogue: FC(h_{T-1}) from lane31's rz stream (no xg term)
    {
        float a0 = bA0, a1 = 0.f;
#pragma unroll
        for (int m = 0; m < 16; m += 2) {
            a0 = dot2(hs[m],     wA[m],     a0);
            a1 = dot2(hs[m + 1], wA[m + 1], a1);
        }
        if (li == 31) outb[(size_t)(TT - 1) * 2 + half] = a0 + a1;
    }
}

// ---------------- fallback (round-3 kernel, used if ws too small) ----------------
__global__ __launch_bounds__(64, 1) void gru_pair_kernel(
    const float* __restrict__ x, const float* __restrict__ W_ih,
    const float* __restrict__ W_hh, const float* __restrict__ b_ih,
    const float* __restrict__ b_hh, const float* __restrict__ W_fc,
    const float* __restrict__ b_fc, float* __restrict__ out)
{
    __shared__ _Float16 hbuf[2][32];
    __shared__ _Float16 xbuf[2][2][32];

    const int lane = threadIdx.x & 63;
    const int li   = lane & 31;
    const int half = lane >> 5;
    const int b    = blockIdx.x * 2 + half;
    const bool unit = (li < HH);

    const float* ph0 = unit ? W_hh + (size_t)li * HH            : W_fc;
    const float* ph1 = unit ? W_hh + (size_t)(HH + li) * HH     : W_fc + HH;
    const float* ph2 = unit ? W_hh + (size_t)(2 * HH + li) * HH : nullptr;
    const float* px0 = unit ? W_ih + (size_t)li * HH            : nullptr;
    const float* px1 = unit ? W_ih + (size_t)(HH + li) * HH     : nullptr;
    const float* px2 = unit ? W_ih + (size_t)(2 * HH + li) * HH : nullptr;

    hf2 wh0[16], wh1[16], wh2[16], wx0[16], wx1[16], wx2[16];
#pragma unroll
    for (int m = 0; m < 16; ++m) {
        auto pk = [&](const float* p) -> hf2 {
            hf2 r;
            r.x = p ? (_Float16)p[2 * m] : (_Float16)0.f;
            r.y = (p && (2 * m + 1) < HH) ? (_Float16)p[2 * m + 1] : (_Float16)0.f;
            return r;
        };
        wh0[m] = pk(ph0); wh1[m] = pk(ph1); wh2[m] = pk(ph2);
        wx0[m] = pk(px0); wx1[m] = pk(px1); wx2[m] = pk(px2);
    }

    float arH0, azH0, anH0, anX0;
    if (unit) {
        arH0 = b_ih[li] + b_hh[li];
        azH0 = b_ih[HH + li] + b_hh[HH + li];
        anH0 = b_hh[2 * HH + li];
        anX0 = b_ih[2 * HH + li];
    } else {
        arH0 = b_fc[0]; azH0 = b_fc[1]; anH0 = 0.f; anX0 = 0.f;
    }

    const float* xb   = x + (size_t)b * TT * HH;
    float*       outb = out + (size_t)b * TT * 2;

    hbuf[half][li]    = (_Float16)0.f;
    xbuf[0][half][li] = unit ? (_Float16)xb[li]      : (_Float16)0.f;
    xbuf[1][half][li] = unit ? (_Float16)xb[HH + li] : (_Float16)0.f;
    MEMFENCE;
    float xpre = unit ? xb[(size_t)2 * HH + li] : 0.f;
    float hval = 0.f;

    const int4* HP  = (const int4*)(&hbuf[half][0]);
    const int4* XB0 = (const int4*)(&xbuf[0][half][0]);
    const int4* XB1 = (const int4*)(&xbuf[1][half][0]);

    int4 xq0 = XB0[0], xq1 = XB0[1], xq2 = XB0[2], xq3 = XB0[3];

#pragma unroll 2
    for (int t = 0; t < TT; ++t) {
        int4 hq0 = HP[0], hq1 = HP[1], hq2 = HP[2], hq3 = HP[3];

        float arH = arH0, azH = azH0, anH = anH0;
        float arX = 0.f, azX = 0.f, anX = anX0;
#define STEPM(m, hp, xp) \
        arH = dot2(hp, wh0[m], arH); azH = dot2(hp, wh1[m], azH); \
        anH = dot2(hp, wh2[m], anH); arX = dot2(xp, wx0[m], arX); \
        azX = dot2(xp, wx1[m], azX); anX = dot2(xp, wx2[m], anX);
        STEPM(0,  hq0.x, xq0.x) STEPM(1,  hq0.y, xq0.y)
        STEPM(2,  hq0.z, xq0.z) STEPM(3,  hq0.w, xq0.w)
        STEPM(4,  hq1.x, xq1.x) STEPM(5,  hq1.y, xq1.y)
        STEPM(6,  hq1.z, xq1.z) STEPM(7,  hq1.w, xq1.w)
        STEPM(8,  hq2.x, xq2.x) STEPM(9,  hq2.y, xq2.y)
        STEPM(10, hq2.z, xq2.z) STEPM(11, hq2.w, xq2.w)
        STEPM(12, hq3.x, xq3.x) STEPM(13, hq3.y, xq3.y)
        STEPM(14, hq3.z, xq3.z) STEPM(15, hq3.w, xq3.w)
#undef STEPM

        const float sumr = arH + arX;
        const float sumz = azH + azX;
        if (lane == 31 && t > 0)
            *(float2*)(outb + (size_t)(t - 1) * 2) = make_float2(sumr, sumz);

        const float r    = __fdividef(1.f, 1.f + __expf(-sumr));
        const float z    = __fdividef(1.f, 1.f + __expf(-sumz));
        const float npre = fmaf(r, anH, anX);
        const float nn   = __fdividef(2.f, 1.f + __expf(-2.f * npre)) - 1.f;
        const float hnew = nn + z * (hval - nn);
        hval = unit ? hnew : 0.f;
        hbuf[half][li] = (_Float16)hval;

        xbuf[t & 1][half][li] = unit ? (_Float16)xpre : (_Float16)0.f;
        MEMFENCE;
        int tn = t + 3; if (tn > TT - 1) tn = TT - 1;
        xpre = unit ? xb[(size_t)tn * HH + li] : 0.f;

        const int4* XN = (t & 1) ? XB0 : XB1;
        xq0 = XN[0]; xq1 = XN[1]; xq2 = XN[2]; xq3 = XN[3];
    }

    {
        int4 hq0 = HP[0], hq1 = HP[1], hq2 = HP[2], hq3 = HP[3];
        float f0 = arH0, f1 = azH0;
#define FST(m, hp) f0 = dot2(hp, wh0[m], f0); f1 = dot2(hp, wh1[m], f1);
        FST(0,  hq0.x) FST(1,  hq0.y) FST(2,  hq0.z) FST(3,  hq0.w)
        FST(4,  hq1.x) FST(5,  hq1.y) FST(6,  hq1.z) FST(7,  hq1.w)
        FST(8,  hq2.x) FST(9,  hq2.y) FST(10, hq2.z) FST(11, hq2.w)
        FST(12, hq3.x) FST(13, hq3.y) FST(14, hq3.z) FST(15, hq3.w)
#undef FST
        if (lane == 31)
            *(float2*)(outb + (size_t)(TT - 1) * 2) = make_float2(f0, f1);
    }
}

extern "C" void kernel_launch(void* const* d_in, const int* in_sizes, int n_in,
                              void* d_out, int out_size, void* d_ws, size_t ws_size,
                              hipStream_t stream) {
    const float* x    = (const float*)d_in[0];
    const float* W_ih = (const float*)d_in[1];
    const float* W_hh = (const float*)d_in[2];
    const float* b_ih = (const float*)d_in[3];
    const float* b_hh = (const float*)d_in[4];
    const float* W_fc = (const float*)d_in[5];
    const float* b_fc = (const float*)d_in[6];
    float* out = (float*)d_out;

    if (ws_size >= WS_NEEDED) {
        _Float16* xg = (_Float16*)d_ws;
        int* wpk = (int*)((char*)d_ws + XG_BYTES);
        pack_wih_kernel<<<(WPAIRS + 255) / 256, 256, 0, stream>>>(W_ih, wpk);
        xg_gemm_kernel<<<BB, 128, 0, stream>>>(x, wpk, b_ih, xg);
        gru_rec_kernel<<<BB / 4, 256, 0, stream>>>(xg, W_hh, b_hh, W_fc, b_fc, out);
    } else {
        gru_pair_kernel<<<BB / 2, 64, 0, stream>>>(x, W_ih, W_hh, b_ih, b_hh,
                                                   W_fc, b_fc, out);
    }
}